// Round 4
// baseline (376.875 us; speedup 1.0000x reference)
//
#include <hip/hip_runtime.h>
#include <hip/hip_bf16.h>
#include <stdint.h>

#define NRES 384
#define CPAIR 128
#define NHEAD 4
#define DHEAD 32
#define MROWS (NRES * NRES) /* 147456 */
#define QK_SCALE 0.17677669529663687f
#define LOG2E 1.4426950408889634f
#define QK_L2E (0.17677669529663687f * 1.4426950408889634f)

typedef unsigned short u16;
typedef short bf16x8 __attribute__((ext_vector_type(8)));
typedef float f32x4 __attribute__((ext_vector_type(4)));

__device__ __forceinline__ u16 f2bf(float f) {
  union { float f; uint32_t u; } c; c.f = f;
  uint32_t u = c.u + 0x7fff + ((c.u >> 16) & 1);   // RNE
  return (u16)(u >> 16);
}
__device__ __forceinline__ float bf2f(u16 h) {
  union { uint32_t u; float f; } c; c.u = ((uint32_t)h) << 16; return c.f;
}
__device__ __forceinline__ float fast_exp2(float x) {
#if __has_builtin(__builtin_amdgcn_exp2f)
  return __builtin_amdgcn_exp2f(x);
#else
  return exp2f(x);
#endif
}
__device__ __forceinline__ uint32_t cvt_pk_bf16(float lo, float hi) {
  uint32_t r;
  asm("v_cvt_pk_bf16_f32 %0, %1, %2" : "=v"(r) : "v"(lo), "v"(hi));
  return r;
}

// ---------------------------------------------------------------- prep weights
// WcatT[n][k] = Wcat[k][n], n in [0,576): wq|wk|wv|wg|w_bias|zero-pad. woT too.
// wq pre-scaled by QK_SCALE*log2e, w_bias by log2e (attn softmax runs in exp2).
__global__ void prep_kernel(const float* __restrict__ wq, const float* __restrict__ wk,
                            const float* __restrict__ wv, const float* __restrict__ wg,
                            const float* __restrict__ wb, const float* __restrict__ wo,
                            u16* __restrict__ wcat, u16* __restrict__ wot) {
  int tid = blockIdx.x * blockDim.x + threadIdx.x;
  int stride = gridDim.x * blockDim.x;
  for (int i = tid; i < 576 * 128; i += stride) {
    int n = i >> 7, kk = i & 127;
    float val;
    if (n < 128)      val = wq[kk * 128 + n] * QK_L2E;
    else if (n < 256) val = wk[kk * 128 + (n - 128)];
    else if (n < 384) val = wv[kk * 128 + (n - 256)];
    else if (n < 512) val = wg[kk * 128 + (n - 384)];
    else if (n < 516) val = wb[kk * 4 + (n - 512)] * LOG2E;
    else              val = 0.f;
    wcat[i] = f2bf(val);
  }
  for (int i = tid; i < 128 * 128; i += stride) {
    int n = i >> 7, kk = i & 127;
    wot[i] = f2bf(wo[kk * 128 + n]);
  }
}

// ---------------------------------------------------------------- fused LN + projections
// Block = one 64-row m-tile, 256 threads (4 waves). LN -> xs (bf16). Weight
// chunks staged through a DOUBLE-BUFFERED wsm with the async-STAGE split
// (T14): issue chunk nc+1's global loads BEFORE computing chunk nc; deferred
// ds_write + lgkmcnt(0) + raw s_barrier afterwards (ONE barrier per chunk,
// L2 latency hidden under MFMA+epilogue, epilogue stores stay in flight
// across the barrier). Read path / epilogue identical to the verified
// round-2 kernel. biasL written in TRANSPOSED attn C-operand lane order.
__global__ __launch_bounds__(256) void proj_kernel(
    const float* __restrict__ pair, const float* __restrict__ lnw,
    const float* __restrict__ lnb, const u16* __restrict__ wcat,
    u16* __restrict__ q, u16* __restrict__ k, u16* __restrict__ v,
    u16* __restrict__ g, float* __restrict__ biasL) {
  __shared__ __align__(16) u16 xs[64 * 136];
  __shared__ __align__(16) u16 wsm[2][64 * 136];
  const int m0 = blockIdx.x * 64;
  const int tid = threadIdx.x;
  // ---- LayerNorm: thread handles row tid>>2, quarter tid&3 (32 cols)
  {
    const int row = tid >> 2, q4 = tid & 3;
    const float* pr = pair + (size_t)(m0 + row) * CPAIR + q4 * 32;
    float4 vals[8];
    float s1 = 0.f, s2 = 0.f;
#pragma unroll
    for (int i = 0; i < 8; ++i) {
      vals[i] = ((const float4*)pr)[i];
      s1 += (vals[i].x + vals[i].y) + (vals[i].z + vals[i].w);
      s2 += vals[i].x * vals[i].x + vals[i].y * vals[i].y +
            vals[i].z * vals[i].z + vals[i].w * vals[i].w;
    }
    s1 += __shfl_xor(s1, 1); s1 += __shfl_xor(s1, 2);   // 4 lanes per row
    s2 += __shfl_xor(s2, 1); s2 += __shfl_xor(s2, 2);
    const float mu = s1 * (1.f / 128.f);
    const float rs = rsqrtf(s2 * (1.f / 128.f) - mu * mu + 1e-5f);
    const float* wr = lnw + q4 * 32;
    const float* br = lnb + q4 * 32;
    uint32_t packed[16];
#pragma unroll
    for (int i = 0; i < 8; ++i) {
      float4 w4 = ((const float4*)wr)[i];
      float4 b4 = ((const float4*)br)[i];
      float y0 = (vals[i].x - mu) * rs * w4.x + b4.x;
      float y1 = (vals[i].y - mu) * rs * w4.y + b4.y;
      float y2 = (vals[i].z - mu) * rs * w4.z + b4.z;
      float y3 = (vals[i].w - mu) * rs * w4.w + b4.w;
      packed[i * 2]     = (uint32_t)f2bf(y0) | ((uint32_t)f2bf(y1) << 16);
      packed[i * 2 + 1] = (uint32_t)f2bf(y2) | ((uint32_t)f2bf(y3) << 16);
    }
#pragma unroll
    for (int i = 0; i < 4; ++i)
      *(uint4*)&xs[row * 136 + q4 * 32 + i * 8] = *(uint4*)&packed[i * 4];
  }
  const int w = tid >> 6, lane = tid & 63, lm = lane & 15, quad = lane >> 4;
  const int srow = tid >> 4, scol8 = (tid & 15) * 8;   // staging coords (c = tid + i*256)

  // prologue: stage chunk 0 synchronously (also publishes xs)
  {
    uint4 st[4];
#pragma unroll
    for (int i = 0; i < 4; ++i)
      st[i] = *(const uint4*)&wcat[(size_t)(srow + i * 16) * CPAIR + scol8];
#pragma unroll
    for (int i = 0; i < 4; ++i)
      *(uint4*)&wsm[0][(srow + i * 16) * 136 + scol8] = st[i];
  }
  __syncthreads();

  // hoist A fragments (xs never changes)
  bf16x8 a[4];
#pragma unroll
  for (int ks = 0; ks < 4; ++ks)
    a[ks] = *(const bf16x8*)&xs[(w * 16 + lm) * 136 + ks * 32 + quad * 8];

  for (int nc = 0; nc < 9; ++nc) {
    const int cur = nc & 1;
    const bool pf = (nc + 1) < 9;
    uint4 st[4];
    if (pf) {   // issue next chunk's loads NOW; consumed after compute
#pragma unroll
      for (int i = 0; i < 4; ++i)
        st[i] = *(const uint4*)&wcat[(size_t)((nc + 1) * 64 + srow + i * 16) * CPAIR + scol8];
    }
    f32x4 acc[4] = {{0, 0, 0, 0}, {0, 0, 0, 0}, {0, 0, 0, 0}, {0, 0, 0, 0}};
#pragma unroll
    for (int ks = 0; ks < 4; ++ks) {
#pragma unroll
      for (int nt = 0; nt < 4; ++nt) {
        bf16x8 bb = *(const bf16x8*)&wsm[cur][(nt * 16 + lm) * 136 + ks * 32 + quad * 8];
        acc[nt] = __builtin_amdgcn_mfma_f32_16x16x32_bf16(a[ks], bb, acc[nt], 0, 0, 0);
      }
    }
#pragma unroll
    for (int nt = 0; nt < 4; ++nt) {
      int n = nc * 64 + nt * 16 + lm;
#pragma unroll
      for (int r = 0; r < 4; ++r) {
        size_t m = (size_t)(m0 + w * 16 + quad * 4 + r);
        float val = acc[nt][r];
        if (n < 128)      q[m * CPAIR + n] = f2bf(val);   // scale folded into wq
        else if (n < 256) k[m * CPAIR + (n - 128)] = f2bf(val);
        else if (n < 384) v[m * CPAIR + (n - 256)] = f2bf(val);
        else if (n < 512) g[m * CPAIR + (n - 384)] = f2bf(1.f / (1.f + __expf(-val)));
        else if (n < 516) {
          int h = n - 512;
          int q_idx = (int)(m / NRES), k_idx = (int)(m % NRES);
          int qt = q_idx >> 6, l6 = q_idx & 63;
          int ww = l6 >> 4, lmq = l6 & 15;                 // q -> (wave-row, lm)
          int t = k_idx >> 4, qk = (k_idx >> 2) & 3, rk = k_idx & 3;  // k -> (tile, quad, reg)
          size_t idx = ((size_t)((h * 6 + qt) * 24 + t) * 256 +
                        (ww * 64 + qk * 16 + lmq)) * 4 + rk;
          biasL[idx] = val;   // log2e folded into wb
        }
      }
    }
    if (pf) {
      // deferred LDS write of the prefetched chunk; compiler auto-inserts the
      // counted vmcnt before the ds_write. lgkmcnt(0)+raw barrier publishes it
      // WITHOUT draining the epilogue's global stores (no vmcnt(0)).
#pragma unroll
      for (int i = 0; i < 4; ++i)
        *(uint4*)&wsm[cur ^ 1][(srow + i * 16) * 136 + scol8] = st[i];
      asm volatile("s_waitcnt lgkmcnt(0)" ::: "memory");
      __builtin_amdgcn_s_barrier();
    }
  }
}

// ---------------------------------------------------------------- attention
// block=(b,h), 512 threads (8 waves). Swapped QK^T: S^T = mfma(K,Q,bias^T) so
// lane (quad,lm) holds P[k = t*16+quad*4+r][q=lm]. Under the contraction
// permutation pi(8q+e) = 4q+e (e<4) / 16+4q+(e-4) (e>=4), the naturally
// packed dwords {pk(r0,r1),pk(r2,r3)} x {tl=0,1} ARE a valid PV A-fragment
// -- zero cross-lane ops. Vt is staged with the matching pi column map, so
// attn-side read addresses are identical to the verified baseline.
// Unnormalized exp2-domain softmax (scales folded into wq/wb at prep);
// O scaled by 1/rsum in epilogue. Waves 0-3: qt 0-2; waves 4-7: qt 3-5.
// LDS 56 KB -> 2 blocks/CU = 16 waves/CU (4/SIMD).
__global__ __launch_bounds__(512, 4) void attn_kernel(
    const u16* __restrict__ q, const u16* __restrict__ k, const u16* __restrict__ v,
    const u16* __restrict__ g, const float* __restrict__ biasL, const int* __restrict__ mask,
    u16* __restrict__ og) {
  __shared__ __align__(16) u16 Ks[NRES * 40];    // [kk][dh] stride 40   (30.7 KB)
  __shared__ __align__(16) u16 Vt[DHEAD * 392];  // [dh][kk] pi-permuted (25.1 KB)
  __shared__ __align__(16) float msk[NRES];      // 1.0 keep / 0.0 masked (1.5 KB)

  const int b = blockIdx.x, h = blockIdx.y;
  const int tid = threadIdx.x;
  const int w = tid >> 6, lane = tid & 63, lm = lane & 15, quad = lane >> 4;
  const int wv = w & 3, hi = w >> 2;

  const u16* kb = k + (size_t)(b * NRES) * CPAIR + h * DHEAD;
  const u16* vb = v + (size_t)(b * NRES) * CPAIR + h * DHEAD;
  for (int i = tid; i < NRES * 4; i += 512) {
    int kk = i >> 2, c8 = (i & 3) * 8;
    *(uint4*)&Ks[kk * 40 + c8] = *(const uint4*)&kb[(size_t)kk * CPAIR + c8];
  }
  // Vt staging with pi column map: element kk lands in group G = c*4+quad
  // (quad = (kk>>2)&3), slot e = (kk&3) + 4*tl (tl = (kk>>4)&1), XOR-swizzled
  // by d8 for bank-conflict-free b128 reads (identical read addresses as before).
  for (int i = tid; i < NRES * 4; i += 512) {
    int d8 = i & 3, kk = i >> 2;
    bf16x8 val = *(const bf16x8*)&vb[(size_t)kk * CPAIR + d8 * 8];
    int G = (kk >> 5) * 4 + ((kk >> 2) & 3);
    int e = (kk & 3) + 4 * ((kk >> 4) & 1);
    int col = (((G ^ d8) << 3) | e);
#pragma unroll
    for (int j = 0; j < 8; ++j) Vt[(d8 * 8 + j) * 392 + col] = (u16)val[j];
  }
  for (int i = tid; i < NRES; i += 512)
    msk[i] = (mask[b * NRES + i] > 0) ? 1.f : 0.f;
  __syncthreads();

  const int f0 = lm >> 3, f1 = (lm + 16) >> 3;

  for (int it = 0; it < 3; ++it) {
    const int qt = hi * 3 + it;
    const int q0 = qt * 64;
    bf16x8 af = *(const bf16x8*)&q[(size_t)(b * NRES + q0 + wv * 16 + lm) * CPAIR +
                                   h * DHEAD + quad * 8];
    const float* bptr = biasL + ((size_t)(h * 6 + qt) * 24) * 1024 + (wv * 64 + lane) * 4;
    float rsum = 0.f;
    f32x4 o0 = {0, 0, 0, 0}, o1 = {0, 0, 0, 0};
#pragma unroll
    for (int c = 0; c < 12; ++c) {
      f32x4 s[2];
#pragma unroll
      for (int tl = 0; tl < 2; ++tl) {
        int t = c * 2 + tl;
        bf16x8 kf = *(const bf16x8*)&Ks[(t * 16 + lm) * 40 + quad * 8];
        f32x4 bv = *(const f32x4*)(bptr + t * 1024);
        s[tl] = __builtin_amdgcn_mfma_f32_16x16x32_bf16(kf, af, bv, 0, 0, 0);
      }
      // softmax (exp2 domain); packed pairs are directly the PV A-fragment
      uint32_t pw[4];
#pragma unroll
      for (int tl = 0; tl < 2; ++tl) {
        int t = c * 2 + tl;
        f32x4 m4 = *(const f32x4*)&msk[t * 16 + quad * 4];
        float p0 = fast_exp2(s[tl][0]) * m4[0];
        float p1 = fast_exp2(s[tl][1]) * m4[1];
        float p2 = fast_exp2(s[tl][2]) * m4[2];
        float p3 = fast_exp2(s[tl][3]) * m4[3];
        rsum += (p0 + p1) + (p2 + p3);
        pw[tl * 2]     = cvt_pk_bf16(p0, p1);
        pw[tl * 2 + 1] = cvt_pk_bf16(p2, p3);
      }
      union { uint32_t u[4]; bf16x8 v8; } pf;
      pf.u[0] = pw[0]; pf.u[1] = pw[1]; pf.u[2] = pw[2]; pf.u[3] = pw[3];
      int B0i = c * 4 + quad;
      bf16x8 vt0 = *(const bf16x8*)&Vt[lm * 392 + ((B0i ^ f0) << 3)];
      bf16x8 vt1 = *(const bf16x8*)&Vt[(lm + 16) * 392 + ((B0i ^ f1) << 3)];
      o0 = __builtin_amdgcn_mfma_f32_16x16x32_bf16(pf.v8, vt0, o0, 0, 0, 0);
      o1 = __builtin_amdgcn_mfma_f32_16x16x32_bf16(pf.v8, vt1, o1, 0, 0, 0);
    }
    // rsum: lane holds partial for q=lm over its quad's k; reduce across quads
    rsum += __shfl_xor(rsum, 16);
    rsum += __shfl_xor(rsum, 32);
#pragma unroll
    for (int r = 0; r < 4; ++r) {
      float rall = __shfl(rsum, quad * 4 + r);   // total for q_local = quad*4+r
      float rinv = 1.f / rall;
      size_t mrow = (size_t)(b * NRES + q0 + wv * 16 + quad * 4 + r);
      int c0 = h * DHEAD + lm, c1 = h * DHEAD + 16 + lm;
      float g0 = bf2f(g[mrow * CPAIR + c0]);
      float g1 = bf2f(g[mrow * CPAIR + c1]);
      og[mrow * CPAIR + c0] = f2bf(o0[r] * rinv * g0);
      og[mrow * CPAIR + c1] = f2bf(o1[r] * rinv * g1);
    }
  }
}

// ---------------------------------------------------------------- out = og @ wo
// Block = one 64-row m-tile. og tile AND both wot chunks staged up front
// (wot is only 32 KB) -> ONE barrier for the whole kernel, then pure
// compute + stores. Read path identical to the verified round-2 kernel.
__global__ __launch_bounds__(256) void outproj_kernel(const u16* __restrict__ og,
                                                      const u16* __restrict__ wot,
                                                      float* __restrict__ out) {
  __shared__ __align__(16) u16 xs[64 * 136];
  __shared__ __align__(16) u16 wsm[128 * 136];
  const int m0 = blockIdx.x * 64;
  const int tid = threadIdx.x;
  const int srow = tid >> 4, scol8 = (tid & 15) * 8;
  {
    uint4 xr[4], wr[8];
#pragma unroll
    for (int i = 0; i < 4; ++i)
      xr[i] = *(const uint4*)&og[(size_t)(m0 + srow + i * 16) * CPAIR + scol8];
#pragma unroll
    for (int i = 0; i < 8; ++i)
      wr[i] = *(const uint4*)&wot[(size_t)(srow + i * 16) * CPAIR + scol8];
#pragma unroll
    for (int i = 0; i < 4; ++i)
      *(uint4*)&xs[(srow + i * 16) * 136 + scol8] = xr[i];
#pragma unroll
    for (int i = 0; i < 8; ++i)
      *(uint4*)&wsm[(srow + i * 16) * 136 + scol8] = wr[i];
  }
  __syncthreads();
  const int w = tid >> 6, lane = tid & 63, lm = lane & 15, quad = lane >> 4;
  bf16x8 a[4];
#pragma unroll
  for (int ks = 0; ks < 4; ++ks)
    a[ks] = *(const bf16x8*)&xs[(w * 16 + lm) * 136 + ks * 32 + quad * 8];
#pragma unroll
  for (int nc = 0; nc < 2; ++nc) {
    f32x4 acc[4] = {{0, 0, 0, 0}, {0, 0, 0, 0}, {0, 0, 0, 0}, {0, 0, 0, 0}};
#pragma unroll
    for (int ks = 0; ks < 4; ++ks) {
#pragma unroll
      for (int nt = 0; nt < 4; ++nt) {
        bf16x8 bb = *(const bf16x8*)&wsm[(nc * 64 + nt * 16 + lm) * 136 + ks * 32 + quad * 8];
        acc[nt] = __builtin_amdgcn_mfma_f32_16x16x32_bf16(a[ks], bb, acc[nt], 0, 0, 0);
      }
    }
#pragma unroll
    for (int nt = 0; nt < 4; ++nt) {
      int n = nc * 64 + nt * 16 + lm;
#pragma unroll
      for (int r = 0; r < 4; ++r) {
        size_t m = (size_t)(m0 + w * 16 + quad * 4 + r);
        out[m * CPAIR + n] = acc[nt][r];
      }
    }
  }
}

// ---------------------------------------------------------------- launch
extern "C" void kernel_launch(void* const* d_in, const int* in_sizes, int n_in,
                              void* d_out, int out_size, void* d_ws, size_t ws_size,
                              hipStream_t stream) {
  const float* pair = (const float*)d_in[0];
  const int* mask = (const int*)d_in[1];
  const float* ln_w = (const float*)d_in[2];
  const float* ln_b = (const float*)d_in[3];
  const float* w_bias = (const float*)d_in[4];
  const float* wq = (const float*)d_in[5];
  const float* wk = (const float*)d_in[6];
  const float* wv = (const float*)d_in[7];
  const float* wg = (const float*)d_in[8];
  const float* wo = (const float*)d_in[9];
  float* out = (float*)d_out;

  // d_out doubles as scratch for q + gate; both dead before outproj writes out.
  u16* qb = (u16*)d_out;
  u16* gb = qb + (size_t)MROWS * CPAIR;

  char* ws = (char*)d_ws;
  const size_t SZ = (size_t)MROWS * CPAIR * 2;  // one bf16 [M][128] buffer
  u16* og = (u16*)(ws);
  u16* kb = (u16*)(ws + SZ);
  u16* vb = (u16*)(ws + 2 * SZ);
  float* biasL = (float*)(ws + 3 * SZ);                       // [H][M] f32, lane order
  u16* wcat = (u16*)(ws + 3 * SZ + (size_t)NHEAD * MROWS * 4);
  u16* wot = wcat + 576 * 128;

  hipLaunchKernelGGL(prep_kernel, dim3(64), dim3(256), 0, stream,
                     wq, wk, wv, wg, w_bias, wo, wcat, wot);
  hipLaunchKernelGGL(proj_kernel, dim3(MROWS / 64), dim3(256), 0, stream,
                     pair, ln_w, ln_b, wcat, qb, kb, vb, gb, biasL);
  hipLaunchKernelGGL(attn_kernel, dim3(NRES, NHEAD), dim3(512), 0, stream,
                     qb, kb, vb, gb, biasL, mask, og);
  hipLaunchKernelGGL(outproj_kernel, dim3(MROWS / 64), dim3(256), 0, stream,
                     og, wot, out);
}

// Round 5
// 285.055 us; speedup vs baseline: 1.3221x; 1.3221x over previous
//
#include <hip/hip_runtime.h>
#include <hip/hip_bf16.h>
#include <stdint.h>

#define NRES 384
#define CPAIR 128
#define NHEAD 4
#define DHEAD 32
#define MROWS (NRES * NRES) /* 147456 */
#define QK_SCALE 0.17677669529663687f
#define LOG2E 1.4426950408889634f
#define QK_L2E (0.17677669529663687f * 1.4426950408889634f)

typedef unsigned short u16;
typedef short bf16x8 __attribute__((ext_vector_type(8)));
typedef float f32x4 __attribute__((ext_vector_type(4)));

__device__ __forceinline__ u16 f2bf(float f) {
  union { float f; uint32_t u; } c; c.f = f;
  uint32_t u = c.u + 0x7fff + ((c.u >> 16) & 1);   // RNE
  return (u16)(u >> 16);
}
__device__ __forceinline__ float bf2f(u16 h) {
  union { uint32_t u; float f; } c; c.u = ((uint32_t)h) << 16; return c.f;
}
__device__ __forceinline__ float fast_exp2(float x) {
#if __has_builtin(__builtin_amdgcn_exp2f)
  return __builtin_amdgcn_exp2f(x);
#else
  return exp2f(x);
#endif
}
__device__ __forceinline__ uint32_t cvt_pk_bf16(float lo, float hi) {
  uint32_t r;
  asm("v_cvt_pk_bf16_f32 %0, %1, %2" : "=v"(r) : "v"(lo), "v"(hi));
  return r;
}

// ---------------------------------------------------------------- prep weights
// WcatT[n][k] = Wcat[k][n], n in [0,576): wq|wk|wv|wg|w_bias|zero-pad. woT too.
// wq pre-scaled by QK_SCALE*log2e, w_bias by log2e (attn softmax runs in exp2).
__global__ void prep_kernel(const float* __restrict__ wq, const float* __restrict__ wk,
                            const float* __restrict__ wv, const float* __restrict__ wg,
                            const float* __restrict__ wb, const float* __restrict__ wo,
                            u16* __restrict__ wcat, u16* __restrict__ wot) {
  int tid = blockIdx.x * blockDim.x + threadIdx.x;
  int stride = gridDim.x * blockDim.x;
  for (int i = tid; i < 576 * 128; i += stride) {
    int n = i >> 7, kk = i & 127;
    float val;
    if (n < 128)      val = wq[kk * 128 + n] * QK_L2E;
    else if (n < 256) val = wk[kk * 128 + (n - 128)];
    else if (n < 384) val = wv[kk * 128 + (n - 256)];
    else if (n < 512) val = wg[kk * 128 + (n - 384)];
    else if (n < 516) val = wb[kk * 4 + (n - 512)] * LOG2E;
    else              val = 0.f;
    wcat[i] = f2bf(val);
  }
  for (int i = tid; i < 128 * 128; i += stride) {
    int n = i >> 7, kk = i & 127;
    wot[i] = f2bf(wo[kk * 128 + n]);
  }
}

// ---------------------------------------------------------------- fused LN + projections
// EXACT round-2 (306us) structure: block = one 64-row m-tile. LN -> xs (bf16).
// 9 n-chunks of wcat staged through wsm (x staged ONCE). biasL written in
// TRANSPOSED attn C-operand lane order (S^T = K*Q^T).
__global__ __launch_bounds__(256) void proj_kernel(
    const float* __restrict__ pair, const float* __restrict__ lnw,
    const float* __restrict__ lnb, const u16* __restrict__ wcat,
    u16* __restrict__ q, u16* __restrict__ k, u16* __restrict__ v,
    u16* __restrict__ g, float* __restrict__ biasL) {
  __shared__ __align__(16) u16 xs[64 * 136];
  __shared__ __align__(16) u16 wsm[64 * 136];
  const int m0 = blockIdx.x * 64;
  const int tid = threadIdx.x;
  // ---- LayerNorm: thread handles row tid>>2, quarter tid&3 (32 cols)
  {
    const int row = tid >> 2, q4 = tid & 3;
    const float* pr = pair + (size_t)(m0 + row) * CPAIR + q4 * 32;
    float4 vals[8];
    float s1 = 0.f, s2 = 0.f;
#pragma unroll
    for (int i = 0; i < 8; ++i) {
      vals[i] = ((const float4*)pr)[i];
      s1 += (vals[i].x + vals[i].y) + (vals[i].z + vals[i].w);
      s2 += vals[i].x * vals[i].x + vals[i].y * vals[i].y +
            vals[i].z * vals[i].z + vals[i].w * vals[i].w;
    }
    s1 += __shfl_xor(s1, 1); s1 += __shfl_xor(s1, 2);   // 4 lanes per row
    s2 += __shfl_xor(s2, 1); s2 += __shfl_xor(s2, 2);
    const float mu = s1 * (1.f / 128.f);
    const float rs = rsqrtf(s2 * (1.f / 128.f) - mu * mu + 1e-5f);
    const float* wr = lnw + q4 * 32;
    const float* br = lnb + q4 * 32;
    uint32_t packed[16];
#pragma unroll
    for (int i = 0; i < 8; ++i) {
      float4 w4 = ((const float4*)wr)[i];
      float4 b4 = ((const float4*)br)[i];
      float y0 = (vals[i].x - mu) * rs * w4.x + b4.x;
      float y1 = (vals[i].y - mu) * rs * w4.y + b4.y;
      float y2 = (vals[i].z - mu) * rs * w4.z + b4.z;
      float y3 = (vals[i].w - mu) * rs * w4.w + b4.w;
      packed[i * 2]     = (uint32_t)f2bf(y0) | ((uint32_t)f2bf(y1) << 16);
      packed[i * 2 + 1] = (uint32_t)f2bf(y2) | ((uint32_t)f2bf(y3) << 16);
    }
#pragma unroll
    for (int i = 0; i < 4; ++i)
      *(uint4*)&xs[row * 136 + q4 * 32 + i * 8] = *(uint4*)&packed[i * 4];
  }
  const int w = tid >> 6, lane = tid & 63, lm = lane & 15, quad = lane >> 4;
  for (int nc = 0; nc < 9; ++nc) {
    __syncthreads();  // prior chunk's MFMA done reading wsm
#pragma unroll
    for (int i = 0; i < 4; ++i) {
      int c = tid + i * 256;
      int row = c >> 4, col8 = (c & 15) * 8;
      *(uint4*)&wsm[row * 136 + col8] =
          *(const uint4*)&wcat[(size_t)(nc * 64 + row) * CPAIR + col8];
    }
    __syncthreads();  // wsm (and, first iter, xs) visible
    f32x4 acc[4] = {{0, 0, 0, 0}, {0, 0, 0, 0}, {0, 0, 0, 0}, {0, 0, 0, 0}};
#pragma unroll
    for (int ks = 0; ks < 4; ++ks) {
      bf16x8 a = *(const bf16x8*)&xs[(w * 16 + lm) * 136 + ks * 32 + quad * 8];
#pragma unroll
      for (int nt = 0; nt < 4; ++nt) {
        bf16x8 bb = *(const bf16x8*)&wsm[(nt * 16 + lm) * 136 + ks * 32 + quad * 8];
        acc[nt] = __builtin_amdgcn_mfma_f32_16x16x32_bf16(a, bb, acc[nt], 0, 0, 0);
      }
    }
#pragma unroll
    for (int nt = 0; nt < 4; ++nt) {
      int n = nc * 64 + nt * 16 + lm;
#pragma unroll
      for (int r = 0; r < 4; ++r) {
        size_t m = (size_t)(m0 + w * 16 + quad * 4 + r);
        float val = acc[nt][r];
        if (n < 128)      q[m * CPAIR + n] = f2bf(val);   // scale folded into wq
        else if (n < 256) k[m * CPAIR + (n - 128)] = f2bf(val);
        else if (n < 384) v[m * CPAIR + (n - 256)] = f2bf(val);
        else if (n < 512) g[m * CPAIR + (n - 384)] = f2bf(1.f / (1.f + __expf(-val)));
        else if (n < 516) {
          int h = n - 512;
          int q_idx = (int)(m / NRES), k_idx = (int)(m % NRES);
          int qt = q_idx >> 6, l6 = q_idx & 63;
          int ww = l6 >> 4, lmq = l6 & 15;                 // q -> (wave-row, lm)
          int t = k_idx >> 4, qk = (k_idx >> 2) & 3, rk = k_idx & 3;  // k -> (tile, quad, reg)
          size_t idx = ((size_t)((h * 6 + qt) * 24 + t) * 256 +
                        (ww * 64 + qk * 16 + lmq)) * 4 + rk;
          biasL[idx] = val;   // log2e folded into wb
        }
      }
    }
  }
}

// ---------------------------------------------------------------- attention
// block=(b,h), 512 threads (8 waves). Swapped QK^T + pi-permuted Vt (round-2
// verified). New this round: (1) depth-2 rotating register prefetch of the
// bias C-operand (global f32x4 loaded 2 c-iters early -- the measured stall);
// (2) mask folded into the MFMA C-operand as 0/-4096 (exp2 underflows to
// exact 0), removing the mask-mul from the exp->pack critical path;
// (3) gate loads hoisted before the c-loop; (4) s_setprio around MFMA pairs.
__global__ __launch_bounds__(512, 4) void attn_kernel(
    const u16* __restrict__ q, const u16* __restrict__ k, const u16* __restrict__ v,
    const u16* __restrict__ g, const float* __restrict__ biasL, const int* __restrict__ mask,
    u16* __restrict__ og) {
  __shared__ __align__(16) u16 Ks[NRES * 40];    // [kk][dh] stride 40   (30.7 KB)
  __shared__ __align__(16) u16 Vt[DHEAD * 392];  // [dh][kk] pi-permuted (25.1 KB)
  __shared__ __align__(16) float mskb[NRES];     // 0.0 keep / -4096.0 masked

  const int b = blockIdx.x, h = blockIdx.y;
  const int tid = threadIdx.x;
  const int w = tid >> 6, lane = tid & 63, lm = lane & 15, quad = lane >> 4;
  const int wv = w & 3, hi = w >> 2;

  const u16* kb = k + (size_t)(b * NRES) * CPAIR + h * DHEAD;
  const u16* vb = v + (size_t)(b * NRES) * CPAIR + h * DHEAD;
  for (int i = tid; i < NRES * 4; i += 512) {
    int kk = i >> 2, c8 = (i & 3) * 8;
    *(uint4*)&Ks[kk * 40 + c8] = *(const uint4*)&kb[(size_t)kk * CPAIR + c8];
  }
  // Vt staging with pi column map (round-2 verified): G = (kk>>5)*4+((kk>>2)&3),
  // e = (kk&3)+4*((kk>>4)&1), XOR-swizzled by d8.
  for (int i = tid; i < NRES * 4; i += 512) {
    int d8 = i & 3, kk = i >> 2;
    bf16x8 val = *(const bf16x8*)&vb[(size_t)kk * CPAIR + d8 * 8];
    int G = (kk >> 5) * 4 + ((kk >> 2) & 3);
    int e = (kk & 3) + 4 * ((kk >> 4) & 1);
    int col = (((G ^ d8) << 3) | e);
#pragma unroll
    for (int j = 0; j < 8; ++j) Vt[(d8 * 8 + j) * 392 + col] = (u16)val[j];
  }
  for (int i = tid; i < NRES; i += 512)
    mskb[i] = (mask[b * NRES + i] > 0) ? 0.f : -4096.f;
  __syncthreads();

  const int f0 = lm >> 3, f1 = (lm + 16) >> 3;

  for (int it = 0; it < 3; ++it) {
    const int qt = hi * 3 + it;
    const int q0 = qt * 64;
    bf16x8 af = *(const bf16x8*)&q[(size_t)(b * NRES + q0 + wv * 16 + lm) * CPAIR +
                                   h * DHEAD + quad * 8];
    const float* bptr = biasL + ((size_t)(h * 6 + qt) * 24) * 1024 + (wv * 64 + lane) * 4;

    // hoist gate loads (consumed only in the epilogue)
    float gv0[4], gv1[4];
#pragma unroll
    for (int r = 0; r < 4; ++r) {
      size_t mrow = (size_t)(b * NRES + q0 + wv * 16 + quad * 4 + r);
      gv0[r] = bf2f(g[mrow * CPAIR + h * DHEAD + lm]);
      gv1[r] = bf2f(g[mrow * CPAIR + h * DHEAD + 16 + lm]);
    }

    // depth-2 rotating bias prefetch (statically indexed under full unroll)
    f32x4 bvp[2][2];
    bvp[0][0] = *(const f32x4*)(bptr + 0 * 1024);
    bvp[0][1] = *(const f32x4*)(bptr + 1 * 1024);
    bvp[1][0] = *(const f32x4*)(bptr + 2 * 1024);
    bvp[1][1] = *(const f32x4*)(bptr + 3 * 1024);

    float rsum = 0.f;
    f32x4 o0 = {0, 0, 0, 0}, o1 = {0, 0, 0, 0};
#pragma unroll
    for (int c = 0; c < 12; ++c) {
      const int t0 = c * 2, t1 = c * 2 + 1;
      // C-operands with mask folded in (off the critical path)
      f32x4 mq0 = *(const f32x4*)&mskb[t0 * 16 + quad * 4];
      f32x4 mq1 = *(const f32x4*)&mskb[t1 * 16 + quad * 4];
      f32x4 cv0 = bvp[c & 1][0] + mq0;
      f32x4 cv1 = bvp[c & 1][1] + mq1;
      if (c < 10) {   // prefetch bias for c+2
        bvp[c & 1][0] = *(const f32x4*)(bptr + (t0 + 4) * 1024);
        bvp[c & 1][1] = *(const f32x4*)(bptr + (t1 + 4) * 1024);
      }
      bf16x8 kf0 = *(const bf16x8*)&Ks[(t0 * 16 + lm) * 40 + quad * 8];
      bf16x8 kf1 = *(const bf16x8*)&Ks[(t1 * 16 + lm) * 40 + quad * 8];
      __builtin_amdgcn_s_setprio(1);
      f32x4 s0 = __builtin_amdgcn_mfma_f32_16x16x32_bf16(kf0, af, cv0, 0, 0, 0);
      f32x4 s1 = __builtin_amdgcn_mfma_f32_16x16x32_bf16(kf1, af, cv1, 0, 0, 0);
      __builtin_amdgcn_s_setprio(0);
      // softmax (exp2 domain); masked entries underflow to exact 0
      float p00 = fast_exp2(s0[0]), p01 = fast_exp2(s0[1]);
      float p02 = fast_exp2(s0[2]), p03 = fast_exp2(s0[3]);
      float p10 = fast_exp2(s1[0]), p11 = fast_exp2(s1[1]);
      float p12 = fast_exp2(s1[2]), p13 = fast_exp2(s1[3]);
      rsum += ((p00 + p01) + (p02 + p03)) + ((p10 + p11) + (p12 + p13));
      union { uint32_t u[4]; bf16x8 v8; } pf;
      pf.u[0] = cvt_pk_bf16(p00, p01);
      pf.u[1] = cvt_pk_bf16(p02, p03);
      pf.u[2] = cvt_pk_bf16(p10, p11);
      pf.u[3] = cvt_pk_bf16(p12, p13);
      int B0i = c * 4 + quad;
      bf16x8 vt0 = *(const bf16x8*)&Vt[lm * 392 + ((B0i ^ f0) << 3)];
      bf16x8 vt1 = *(const bf16x8*)&Vt[(lm + 16) * 392 + ((B0i ^ f1) << 3)];
      __builtin_amdgcn_s_setprio(1);
      o0 = __builtin_amdgcn_mfma_f32_16x16x32_bf16(pf.v8, vt0, o0, 0, 0, 0);
      o1 = __builtin_amdgcn_mfma_f32_16x16x32_bf16(pf.v8, vt1, o1, 0, 0, 0);
      __builtin_amdgcn_s_setprio(0);
    }
    // rsum: lane holds partial for q=lm over its quad's k; reduce across quads
    rsum += __shfl_xor(rsum, 16);
    rsum += __shfl_xor(rsum, 32);
#pragma unroll
    for (int r = 0; r < 4; ++r) {
      float rall = __shfl(rsum, quad * 4 + r);   // total for q_local = quad*4+r
      float rinv = 1.f / rall;
      size_t mrow = (size_t)(b * NRES + q0 + wv * 16 + quad * 4 + r);
      int c0 = h * DHEAD + lm, c1 = h * DHEAD + 16 + lm;
      og[mrow * CPAIR + c0] = f2bf(o0[r] * rinv * gv0[r]);
      og[mrow * CPAIR + c1] = f2bf(o1[r] * rinv * gv1[r]);
    }
  }
}

// ---------------------------------------------------------------- out = og @ wo
// EXACT round-2 (306us) structure: block = one 64-row m-tile; og staged once,
// 2 n-chunks of wot looped.
__global__ __launch_bounds__(256) void outproj_kernel(const u16* __restrict__ og,
                                                      const u16* __restrict__ wot,
                                                      float* __restrict__ out) {
  __shared__ __align__(16) u16 xs[64 * 136];
  __shared__ __align__(16) u16 wsm[64 * 136];
  const int m0 = blockIdx.x * 64;
  const int tid = threadIdx.x;
#pragma unroll
  for (int i = 0; i < 4; ++i) {
    int c = tid + i * 256;
    int row = c >> 4, col8 = (c & 15) * 8;
    *(uint4*)&xs[row * 136 + col8] = *(const uint4*)&og[(size_t)(m0 + row) * CPAIR + col8];
  }
  const int w = tid >> 6, lane = tid & 63, lm = lane & 15, quad = lane >> 4;
  for (int nc = 0; nc < 2; ++nc) {
    __syncthreads();
#pragma unroll
    for (int i = 0; i < 4; ++i) {
      int c = tid + i * 256;
      int row = c >> 4, col8 = (c & 15) * 8;
      *(uint4*)&wsm[row * 136 + col8] =
          *(const uint4*)&wot[(size_t)(nc * 64 + row) * CPAIR + col8];
    }
    __syncthreads();
    f32x4 acc[4] = {{0, 0, 0, 0}, {0, 0, 0, 0}, {0, 0, 0, 0}, {0, 0, 0, 0}};
#pragma unroll
    for (int ks = 0; ks < 4; ++ks) {
      bf16x8 a = *(const bf16x8*)&xs[(w * 16 + lm) * 136 + ks * 32 + quad * 8];
#pragma unroll
      for (int nt = 0; nt < 4; ++nt) {
        bf16x8 bb = *(const bf16x8*)&wsm[(nt * 16 + lm) * 136 + ks * 32 + quad * 8];
        acc[nt] = __builtin_amdgcn_mfma_f32_16x16x32_bf16(a, bb, acc[nt], 0, 0, 0);
      }
    }
#pragma unroll
    for (int nt = 0; nt < 4; ++nt) {
      int n = nc * 64 + nt * 16 + lm;
#pragma unroll
      for (int r = 0; r < 4; ++r) {
        size_t m = (size_t)(m0 + w * 16 + quad * 4 + r);
        out[m * CPAIR + n] = acc[nt][r];
      }
    }
  }
}

// ---------------------------------------------------------------- launch
extern "C" void kernel_launch(void* const* d_in, const int* in_sizes, int n_in,
                              void* d_out, int out_size, void* d_ws, size_t ws_size,
                              hipStream_t stream) {
  const float* pair = (const float*)d_in[0];
  const int* mask = (const int*)d_in[1];
  const float* ln_w = (const float*)d_in[2];
  const float* ln_b = (const float*)d_in[3];
  const float* w_bias = (const float*)d_in[4];
  const float* wq = (const float*)d_in[5];
  const float* wk = (const float*)d_in[6];
  const float* wv = (const float*)d_in[7];
  const float* wg = (const float*)d_in[8];
  const float* wo = (const float*)d_in[9];
  float* out = (float*)d_out;

  // d_out doubles as scratch for q + gate; both dead before outproj writes out.
  u16* qb = (u16*)d_out;
  u16* gb = qb + (size_t)MROWS * CPAIR;

  char* ws = (char*)d_ws;
  const size_t SZ = (size_t)MROWS * CPAIR * 2;  // one bf16 [M][128] buffer
  u16* og = (u16*)(ws);
  u16* kb = (u16*)(ws + SZ);
  u16* vb = (u16*)(ws + 2 * SZ);
  float* biasL = (float*)(ws + 3 * SZ);                       // [H][M] f32, lane order
  u16* wcat = (u16*)(ws + 3 * SZ + (size_t)NHEAD * MROWS * 4);
  u16* wot = wcat + 576 * 128;

  hipLaunchKernelGGL(prep_kernel, dim3(64), dim3(256), 0, stream,
                     wq, wk, wv, wg, w_bias, wo, wcat, wot);
  hipLaunchKernelGGL(proj_kernel, dim3(MROWS / 64), dim3(256), 0, stream,
                     pair, ln_w, ln_b, wcat, qb, kb, vb, gb, biasL);
  hipLaunchKernelGGL(attn_kernel, dim3(NRES, NHEAD), dim3(512), 0, stream,
                     qb, kb, vb, gb, biasL, mask, og);
  hipLaunchKernelGGL(outproj_kernel, dim3(MROWS / 64), dim3(256), 0, stream,
                     og, wot, out);
}